// Round 3
// baseline (270.845 us; speedup 1.0000x reference)
//
#include <hip/hip_runtime.h>
#include <hip/hip_bf16.h>

// Problem constants
#define BB 2
#define TT 2048
#define DD 1024
#define NN 16
#define RR 64          // DT_RANK
#define MM (BB*TT)     // 4096 rows
#define KDIM DD        // 1024
#define CHUNK 128
#define NCHUNK (TT/CHUNK)  // 16

// Workspace layout (in floats) — 22.5 MB total (known to fit)
#define BT_OFF 0                      // Bt: MM*NN      = 65536
#define CT_OFF 65536                  // Ct: MM*NN      = 65536
#define R1_OFF 131072                 // R1: MM*RR      = 262144
#define DT_OFF 393216                 // dt: MM*DD      = 4194304
#define P_OFF  4587520                // P : NCHUNK*BB*DD*NN = 524288
#define S_OFF  5111808                // S : same       = 524288

__device__ __forceinline__ float softplus_f(float z) {
    return fmaxf(z, 0.0f) + log1pf(expf(-fabsf(z)));
}

// ---------------------------------------------------------------------------
// Kernel 1: combined projection  [Bt | Ct | R1] = x @ [W_B; W_C; W_dt1]^T
// (unchanged — will tune once counters show its cost)
// ---------------------------------------------------------------------------
__global__ __launch_bounds__(256) void k_proj96(
    const float* __restrict__ x, const float* __restrict__ W_B,
    const float* __restrict__ W_C, const float* __restrict__ W_dt1,
    float* __restrict__ Bt, float* __restrict__ Ct, float* __restrict__ R1)
{
    __shared__ float xs[16][68];
    __shared__ float wsT[16][97];

    const int tid = threadIdx.x;
    const int r0 = blockIdx.x * 64;
    const int kbase = blockIdx.y * 256;
    const int tx = tid & 15;
    const int ty = tid >> 4;

    float acc[4][6];
    #pragma unroll
    for (int i = 0; i < 4; i++)
        #pragma unroll
        for (int j = 0; j < 6; j++) acc[i][j] = 0.0f;

    for (int kc = 0; kc < 256; kc += 16) {
        {
            const int row = tid >> 2;
            const int kq = (tid & 3) * 4;
            float4 v = *(const float4*)(x + (size_t)(r0 + row) * KDIM + kbase + kc + kq);
            xs[kq + 0][row] = v.x; xs[kq + 1][row] = v.y;
            xs[kq + 2][row] = v.z; xs[kq + 3][row] = v.w;
        }
        #pragma unroll
        for (int i = 0; i < 6; i++) {
            const int idx = i * 256 + tid;
            const int c = idx >> 4;
            const int kk = idx & 15;
            const float* wrow; int cc;
            if (c < 16)      { wrow = W_B;   cc = c; }
            else if (c < 32) { wrow = W_C;   cc = c - 16; }
            else             { wrow = W_dt1; cc = c - 32; }
            wsT[kk][c] = wrow[(size_t)cc * KDIM + kbase + kc + kk];
        }
        __syncthreads();
        #pragma unroll
        for (int kk = 0; kk < 16; kk++) {
            const float a0 = xs[kk][ty * 4 + 0];
            const float a1 = xs[kk][ty * 4 + 1];
            const float a2 = xs[kk][ty * 4 + 2];
            const float a3 = xs[kk][ty * 4 + 3];
            #pragma unroll
            for (int j = 0; j < 6; j++) {
                const float b = wsT[kk][tx + j * 16];
                acc[0][j] = fmaf(a0, b, acc[0][j]);
                acc[1][j] = fmaf(a1, b, acc[1][j]);
                acc[2][j] = fmaf(a2, b, acc[2][j]);
                acc[3][j] = fmaf(a3, b, acc[3][j]);
            }
        }
        __syncthreads();
    }

    #pragma unroll
    for (int i = 0; i < 4; i++) {
        const int r = r0 + ty * 4 + i;
        #pragma unroll
        for (int j = 0; j < 6; j++) {
            const int c = tx + j * 16;
            const float v = acc[i][j];
            if (c < 16)      atomicAdd(&Bt[r * NN + c], v);
            else if (c < 32) atomicAdd(&Ct[r * NN + (c - 16)], v);
            else             atomicAdd(&R1[r * RR + (c - 32)], v);
        }
    }
}

// ---------------------------------------------------------------------------
// Kernel 2: dt = softplus(R1 @ W_dt2^T + b_dt2).  (unchanged)
// ---------------------------------------------------------------------------
__global__ __launch_bounds__(256) void k_dtproj(
    const float* __restrict__ R1, const float* __restrict__ W_dt2,
    const float* __restrict__ b_dt2, float* __restrict__ dt)
{
    __shared__ float r1s[16][65];
    __shared__ float wsT[64][256];

    const int tid = threadIdx.x;
    const int r0 = blockIdx.x * 16;
    const int d0 = blockIdx.y * 256;

    {
        const int row = tid >> 4;
        const int kq = (tid & 15) * 4;
        float4 v = *(const float4*)(R1 + (size_t)(r0 + row) * RR + kq);
        r1s[row][kq + 0] = v.x; r1s[row][kq + 1] = v.y;
        r1s[row][kq + 2] = v.z; r1s[row][kq + 3] = v.w;
    }
    {
        const float* src = W_dt2 + (size_t)(d0 + tid) * RR;
        #pragma unroll
        for (int kq = 0; kq < 64; kq += 4) {
            float4 v = *(const float4*)(src + kq);
            wsT[kq + 0][tid] = v.x; wsT[kq + 1][tid] = v.y;
            wsT[kq + 2][tid] = v.z; wsT[kq + 3][tid] = v.w;
        }
    }
    __syncthreads();

    const int r = tid & 15;
    const int dg = tid >> 4;

    float4 acc[4];
    #pragma unroll
    for (int q = 0; q < 4; q++) acc[q] = make_float4(0.f, 0.f, 0.f, 0.f);

    #pragma unroll 4
    for (int k = 0; k < 64; k++) {
        const float a = r1s[r][k];
        #pragma unroll
        for (int q = 0; q < 4; q++) {
            float4 bv = *(const float4*)&wsT[k][dg * 16 + q * 4];
            acc[q].x = fmaf(a, bv.x, acc[q].x);
            acc[q].y = fmaf(a, bv.y, acc[q].y);
            acc[q].z = fmaf(a, bv.z, acc[q].z);
            acc[q].w = fmaf(a, bv.w, acc[q].w);
        }
    }

    float* out = dt + (size_t)(r0 + r) * DD + d0 + dg * 16;
    const float* bb = b_dt2 + d0 + dg * 16;
    #pragma unroll
    for (int q = 0; q < 4; q++) {
        float4 bias = *(const float4*)(bb + q * 4);
        float4 o;
        o.x = softplus_f(acc[q].x + bias.x);
        o.y = softplus_f(acc[q].y + bias.y);
        o.z = softplus_f(acc[q].z + bias.z);
        o.w = softplus_f(acc[q].w + bias.w);
        *(float4*)(out + q * 4) = o;
    }
}

// ---------------------------------------------------------------------------
// Scan kernels, v3: thread owns 4 n-chains of one (b,d,chunk).
// Block 256 = 64 d  x  4 n-groups.  ng = tid&3 (n = ng*4..ng*4+3), dl = tid>>2.
// All chain state (P,S / h) in registers; Bt/Ct staged in LDS (8KB each);
// dt/x read direct from global (coalesced, unroll-prefetched).
// Reduction over n: 4 in-thread FMAs + shfl_xor(1)/shfl_xor(2) = DPP quad_perm
// (full-rate VALU, no LDS pipe).
// ---------------------------------------------------------------------------
__global__ __launch_bounds__(256) void k_scan1(
    const float* __restrict__ x, const float* __restrict__ dt,
    const float* __restrict__ Bt, const float* __restrict__ log_A,
    float* __restrict__ P, float* __restrict__ S)
{
    __shared__ float bt_s[CHUNK][NN];   // 8 KB

    const int tid = threadIdx.x;
    const int ng = tid & 3;
    const int dl = tid >> 2;
    const int d  = blockIdx.x * 64 + dl;
    const int c  = blockIdx.y;
    const int b  = blockIdx.z;
    const int n0 = ng * 4;
    const int base = b * TT + c * CHUNK;

    const float4 lg = *(const float4*)(log_A + d * NN + n0);
    const float A0 = -__expf(lg.x), A1 = -__expf(lg.y),
                A2 = -__expf(lg.z), A3 = -__expf(lg.w);
    const float rA0 = 1.0f / (A0 + 1e-8f), rA1 = 1.0f / (A1 + 1e-8f),
                rA2 = 1.0f / (A2 + 1e-8f), rA3 = 1.0f / (A3 + 1e-8f);

    // stage Bt chunk tile: 128 t x 16 n = 2048 floats = 512 float4
    {
        const float* gbt = Bt + (size_t)base * NN;
        #pragma unroll
        for (int k = 0; k < 2; k++) {
            const int f = tid + k * 256;
            const int t = f >> 2;
            const int j = (f & 3) * 4;
            *(float4*)&bt_s[t][j] = *(const float4*)(gbt + (size_t)t * NN + j);
        }
    }
    __syncthreads();

    const float* dtp = dt + (size_t)base * DD + d;
    const float* xp  = x  + (size_t)base * DD + d;

    float P0 = 1.f, P1 = 1.f, P2 = 1.f, P3 = 1.f;
    float S0 = 0.f, S1 = 0.f, S2 = 0.f, S3 = 0.f;

    #pragma unroll 8
    for (int t = 0; t < CHUNK; t++) {
        const float dtv = dtp[(size_t)t * DD];
        const float xv  = xp[(size_t)t * DD];
        const float4 bt4 = *(const float4*)&bt_s[t][n0];
        const float a0 = __expf(dtv * A0);
        const float a1 = __expf(dtv * A1);
        const float a2 = __expf(dtv * A2);
        const float a3 = __expf(dtv * A3);
        // S = a*S + (a-1)*u  ==  a*(S+u) - u,  u = rA*bt*x
        const float u0 = rA0 * bt4.x * xv;
        const float u1 = rA1 * bt4.y * xv;
        const float u2 = rA2 * bt4.z * xv;
        const float u3 = rA3 * bt4.w * xv;
        S0 = fmaf(a0, S0 + u0, -u0);
        S1 = fmaf(a1, S1 + u1, -u1);
        S2 = fmaf(a2, S2 + u2, -u2);
        S3 = fmaf(a3, S3 + u3, -u3);
        P0 *= a0; P1 *= a1; P2 *= a2; P3 *= a3;
    }

    const int oidx = ((c * BB + b) * DD + d) * NN + n0;
    *(float4*)(P + oidx) = make_float4(P0, P1, P2, P3);
    *(float4*)(S + oidx) = make_float4(S0, S1, S2, S3);
}

__global__ __launch_bounds__(256) void k_scan2(
    const float* __restrict__ x, const float* __restrict__ dt,
    const float* __restrict__ Bt, const float* __restrict__ Ct,
    const float* __restrict__ log_A, const float* __restrict__ D_skip,
    const float* __restrict__ P, const float* __restrict__ S,
    float* __restrict__ y)
{
    __shared__ float bt_s[CHUNK][NN];   // 8 KB
    __shared__ float ct_s[CHUNK][NN];   // 8 KB

    const int tid = threadIdx.x;
    const int ng = tid & 3;
    const int dl = tid >> 2;
    const int d  = blockIdx.x * 64 + dl;
    const int c  = blockIdx.y;
    const int b  = blockIdx.z;
    const int n0 = ng * 4;
    const int base = b * TT + c * CHUNK;

    const float4 lg = *(const float4*)(log_A + d * NN + n0);
    const float A0 = -__expf(lg.x), A1 = -__expf(lg.y),
                A2 = -__expf(lg.z), A3 = -__expf(lg.w);
    const float rA0 = 1.0f / (A0 + 1e-8f), rA1 = 1.0f / (A1 + 1e-8f),
                rA2 = 1.0f / (A2 + 1e-8f), rA3 = 1.0f / (A3 + 1e-8f);
    const float dsk = D_skip[d];

    // stage Bt/Ct chunk tiles (issue loads before the recombine loop)
    {
        const float* gbt = Bt + (size_t)base * NN;
        const float* gct = Ct + (size_t)base * NN;
        #pragma unroll
        for (int k = 0; k < 2; k++) {
            const int f = tid + k * 256;
            const int t = f >> 2;
            const int j = (f & 3) * 4;
            *(float4*)&bt_s[t][j] = *(const float4*)(gbt + (size_t)t * NN + j);
            *(float4*)&ct_s[t][j] = *(const float4*)(gct + (size_t)t * NN + j);
        }
    }

    // h_init from previous chunk transitions (register chains, L2-resident P/S)
    float h0 = 0.f, h1 = 0.f, h2 = 0.f, h3 = 0.f;
    for (int cc = 0; cc < c; cc++) {
        const int idx = ((cc * BB + b) * DD + d) * NN + n0;
        const float4 Pv = *(const float4*)(P + idx);
        const float4 Sv = *(const float4*)(S + idx);
        h0 = fmaf(Pv.x, h0, Sv.x);
        h1 = fmaf(Pv.y, h1, Sv.y);
        h2 = fmaf(Pv.z, h2, Sv.z);
        h3 = fmaf(Pv.w, h3, Sv.w);
    }
    __syncthreads();

    const float* dtp = dt + (size_t)base * DD + d;
    const float* xp  = x  + (size_t)base * DD + d;
    float* yp = y + (size_t)base * DD + d;

    #pragma unroll 8
    for (int t = 0; t < CHUNK; t++) {
        const float dtv = dtp[(size_t)t * DD];
        const float xv  = xp[(size_t)t * DD];
        const float4 bt4 = *(const float4*)&bt_s[t][n0];
        const float4 ct4 = *(const float4*)&ct_s[t][n0];
        const float a0 = __expf(dtv * A0);
        const float a1 = __expf(dtv * A1);
        const float a2 = __expf(dtv * A2);
        const float a3 = __expf(dtv * A3);
        const float u0 = rA0 * bt4.x * xv;
        const float u1 = rA1 * bt4.y * xv;
        const float u2 = rA2 * bt4.z * xv;
        const float u3 = rA3 * bt4.w * xv;
        h0 = fmaf(a0, h0 + u0, -u0);
        h1 = fmaf(a1, h1 + u1, -u1);
        h2 = fmaf(a2, h2 + u2, -u2);
        h3 = fmaf(a3, h3 + u3, -u3);
        float part = fmaf(h3, ct4.w, fmaf(h2, ct4.z, fmaf(h1, ct4.y, h0 * ct4.x)));
        part += __shfl_xor(part, 1);   // DPP quad_perm
        part += __shfl_xor(part, 2);   // DPP quad_perm
        if (ng == 0) yp[(size_t)t * DD] = fmaf(dsk, xv, part);
    }
}

// ---------------------------------------------------------------------------
extern "C" void kernel_launch(void* const* d_in, const int* in_sizes, int n_in,
                              void* d_out, int out_size, void* d_ws, size_t ws_size,
                              hipStream_t stream)
{
    const float* x      = (const float*)d_in[0];
    const float* W_B    = (const float*)d_in[1];
    const float* W_C    = (const float*)d_in[2];
    const float* W_dt1  = (const float*)d_in[3];
    const float* W_dt2  = (const float*)d_in[4];
    const float* b_dt2  = (const float*)d_in[5];
    const float* log_A  = (const float*)d_in[6];
    const float* D_skip = (const float*)d_in[7];
    float* y = (float*)d_out;

    float* ws = (float*)d_ws;
    float* Bt = ws + BT_OFF;
    float* Ct = ws + CT_OFF;
    float* R1 = ws + R1_OFF;
    float* dt = ws + DT_OFF;
    float* P  = ws + P_OFF;
    float* S  = ws + S_OFF;

    hipMemsetAsync(d_ws, 0, (size_t)DT_OFF * sizeof(float), stream);

    k_proj96<<<dim3(MM / 64, 4), 256, 0, stream>>>(x, W_B, W_C, W_dt1, Bt, Ct, R1);
    k_dtproj<<<dim3(MM / 16, DD / 256), 256, 0, stream>>>(R1, W_dt2, b_dt2, dt);
    k_scan1<<<dim3(DD / 64, NCHUNK, BB), 256, 0, stream>>>(x, dt, Bt, log_A, P, S);
    k_scan2<<<dim3(DD / 64, NCHUNK, BB), 256, 0, stream>>>(x, dt, Bt, Ct, log_A, D_skip, P, S, y);
}